// Round 1
// baseline (6280.294 us; speedup 1.0000x reference)
//
#include <hip/hip_runtime.h>
#include <cstdint>
#include <cstddef>

// DecoderLSTM: 2-layer LSTM (B=512,H=512,T=128) + 3-layer MLP head.
// Strategy: bf16 MFMA GEMMs; A-operand carried as bf16 hi+lo (K=2048) for accuracy;
// fp32 cell state; gate-interleaved prepacked weights so elementwise fuses into epilogue.

using u16 = unsigned short;
typedef __attribute__((ext_vector_type(8))) short bf16x8;
typedef __attribute__((ext_vector_type(4))) float f32x4;

#define HID 512
#define BATCH 512
#define SEQ 128

__device__ __forceinline__ u16 f2bf(float f) {
    union { float f; uint32_t u; } v; v.f = f;
    uint32_t u = v.u;
    uint32_t r = (u + 0x7fffu + ((u >> 16) & 1u)) >> 16;
    return (u16)r;
}
__device__ __forceinline__ float bf2f(u16 h) {
    union { uint32_t u; float f; } v; v.u = ((uint32_t)h) << 16;
    return v.f;
}
__device__ __forceinline__ float tanh_fast(float v) {
    float a = fabsf(v);
    float t = __expf(-2.f * a);
    float r = (1.f - t) / (1.f + t);
    return copysignf(r, v);
}
__device__ __forceinline__ float sigmoid_fast(float v) {
    return 1.f / (1.f + __expf(-v));
}

// ---------------------------------------------------------------- prepack ----
// Bpack[l][np][k], np = hcol*4 + gate (gate order i,f,g,o), k: 0..511 = W_ih, 512..1023 = W_hh
__global__ __launch_bounds__(256) void prepack(
    const float* __restrict__ W_ih, const float* __restrict__ W_hh,
    const float* __restrict__ b_ih, const float* __restrict__ b_hh,
    const float* __restrict__ fc1w, const float* __restrict__ fc2w, const float* __restrict__ fc3w,
    u16* __restrict__ Bpack, float* __restrict__ bsumv, u16* __restrict__ fcw)
{
    int stride = gridDim.x * blockDim.x;
    int tid0 = blockIdx.x * blockDim.x + threadIdx.x;
    for (int idx = tid0; idx < 2 * 2048 * 1024; idx += stride) {
        int l = idx >> 21;
        int rem = idx & ((1 << 21) - 1);
        int np = rem >> 10;
        int k = rem & 1023;
        int n = (np & 3) * 512 + (np >> 2);
        float v = (k < 512) ? W_ih[((size_t)l * 2048 + n) * 512 + k]
                            : W_hh[((size_t)l * 2048 + n) * 512 + (k - 512)];
        Bpack[idx] = f2bf(v);
    }
    for (int idx = tid0; idx < 2 * 2048; idx += stride) {
        int l = idx >> 11;
        int np = idx & 2047;
        int n = (np & 3) * 512 + (np >> 2);
        bsumv[idx] = b_ih[l * 2048 + n] + b_hh[l * 2048 + n];
    }
    for (int idx = tid0; idx < 3 * 512 * 512; idx += stride) {
        const float* w = idx < 262144 ? fc1w : (idx < 524288 ? fc2w : fc3w);
        fcw[idx] = f2bf(w[idx & 262143]);
    }
}

// A buffers: [512][2048] bf16: cols [0:512)=x/hsum hi, [512:1024)=h hi, [1024:1536)=x lo, [1536:2048)=h lo
__global__ __launch_bounds__(256) void initbufs(
    const float* __restrict__ x, u16* __restrict__ A0_0, u16* __restrict__ A1_0,
    float* __restrict__ c0, float* __restrict__ c1)
{
    int stride = gridDim.x * blockDim.x;
    int tid0 = blockIdx.x * blockDim.x + threadIdx.x;
    for (int idx = tid0; idx < 512 * 512; idx += stride) {
        int row = idx >> 9, col = idx & 511;
        float xv = x[idx];
        u16 hi = f2bf(xv);
        float lo = xv - bf2f(hi);
        size_t b = (size_t)row * 2048;
        A0_0[b + col] = hi;
        A0_0[b + 1024 + col] = f2bf(lo);
        A0_0[b + 512 + col] = 0;
        A0_0[b + 1536 + col] = 0;
        A1_0[b + 512 + col] = 0;
        A1_0[b + 1536 + col] = 0;
        c0[idx] = 0.f;
        c1[idx] = 0.f;
    }
}

// --------------------------------------------------------------- lstm step ---
// One layer of one timestep. BM=64 (blockIdx.y of 8), BN=128 n'-cols (blockIdx.x of 16).
// gates[64x128] = A[64 x 2048(hi,lo)] @ Bp[2048 n' x 1024 k], then fused c/h update.
template <int IS_L1>
__global__ __launch_bounds__(256) void lstm_step(
    const u16* A, const u16* __restrict__ Bp, const float* __restrict__ bsumv,
    float* cbuf, u16* hdst1, int hoff1, u16* hdst2, int hoff2,
    const u16* h0src, u16* hsumdst, u16* seqdst)
{
    __shared__ char smem[36864];
    u16* sAhi = (u16*)smem;                 // [64][72]
    u16* sAlo = (u16*)(smem + 9216);        // [64][72]
    u16* sB   = (u16*)(smem + 18432);       // [128][72]

    const int tid = threadIdx.x;
    const int lane = tid & 63, wid = tid >> 6;
    const int row0 = blockIdx.y * 64;
    const int n0 = blockIdx.x * 128;
    const int wn = wid * 32;
    const int fm = lane & 15;
    const int fkbase = (lane >> 4) * 8;

    f32x4 acc[4][2];
#pragma unroll
    for (int m = 0; m < 4; ++m) { acc[m][0] = (f32x4)0.f; acc[m][1] = (f32x4)0.f; }

    for (int kk = 0; kk < 16; ++kk) {
        const int k0 = kk * 64;
        __syncthreads();
#pragma unroll
        for (int r = 0; r < 2; ++r) {
            int c = tid + r * 256;
            int row = c >> 3, cc = (c & 7) * 8;
            *(bf16x8*)&sAhi[row * 72 + cc] = *(const bf16x8*)&A[(size_t)(row0 + row) * 2048 + k0 + cc];
            *(bf16x8*)&sAlo[row * 72 + cc] = *(const bf16x8*)&A[(size_t)(row0 + row) * 2048 + 1024 + k0 + cc];
        }
#pragma unroll
        for (int r = 0; r < 4; ++r) {
            int c = tid + r * 256;
            int row = c >> 3, cc = (c & 7) * 8;
            *(bf16x8*)&sB[row * 72 + cc] = *(const bf16x8*)&Bp[(size_t)(n0 + row) * 1024 + k0 + cc];
        }
        __syncthreads();
#pragma unroll
        for (int kf = 0; kf < 2; ++kf) {
            const int kb = kf * 32 + fkbase;
            bf16x8 b0 = *(const bf16x8*)&sB[(wn + fm) * 72 + kb];
            bf16x8 b1 = *(const bf16x8*)&sB[(wn + 16 + fm) * 72 + kb];
#pragma unroll
            for (int m = 0; m < 4; ++m) {
                bf16x8 ah = *(const bf16x8*)&sAhi[(m * 16 + fm) * 72 + kb];
                bf16x8 al = *(const bf16x8*)&sAlo[(m * 16 + fm) * 72 + kb];
                acc[m][0] = __builtin_amdgcn_mfma_f32_16x16x32_bf16(ah, b0, acc[m][0], 0, 0, 0);
                acc[m][1] = __builtin_amdgcn_mfma_f32_16x16x32_bf16(ah, b1, acc[m][1], 0, 0, 0);
                acc[m][0] = __builtin_amdgcn_mfma_f32_16x16x32_bf16(al, b0, acc[m][0], 0, 0, 0);
                acc[m][1] = __builtin_amdgcn_mfma_f32_16x16x32_bf16(al, b1, acc[m][1], 0, 0, 0);
            }
        }
    }

    __syncthreads();
    float* sG = (float*)smem;  // [64][132]
#pragma unroll
    for (int m = 0; m < 4; ++m)
#pragma unroll
        for (int n = 0; n < 2; ++n)
#pragma unroll
            for (int r = 0; r < 4; ++r) {
                int row = m * 16 + (lane >> 4) * 4 + r;
                int col = wn + n * 16 + fm;
                sG[row * 132 + col] = acc[m][n][r];
            }
    __syncthreads();

#pragma unroll
    for (int j = 0; j < 8; ++j) {
        int cell = tid + j * 256;  // 64 rows x 32 hcols
        int row = cell >> 5, hc = cell & 31;
        const float4 g4 = *(const float4*)&sG[row * 132 + hc * 4];
        const float4 b4 = *(const float4*)&bsumv[n0 + hc * 4];
        float gi = g4.x + b4.x, gf = g4.y + b4.y, gg = g4.z + b4.z, go = g4.w + b4.w;
        int grow = row0 + row;
        int ghc = (n0 >> 2) + hc;
        int cidx = grow * 512 + ghc;
        float c_old = cbuf[cidx];
        float is = sigmoid_fast(gi);
        float fs = sigmoid_fast(gf);
        float os = sigmoid_fast(go);
        float gt = tanh_fast(gg);
        float cn = fs * c_old + is * gt;
        float hn = os * tanh_fast(cn);
        cbuf[cidx] = cn;
        u16 hh = f2bf(hn);
        float hlo = hn - bf2f(hh);
        u16 hl = f2bf(hlo);
        size_t base1 = (size_t)grow * 2048 + hoff1;
        hdst1[base1 + ghc] = hh;
        hdst1[base1 + 1024 + ghc] = hl;
        if (!IS_L1) {
            size_t base2 = (size_t)grow * 2048 + hoff2;
            hdst2[base2 + ghc] = hh;
            hdst2[base2 + 1024 + ghc] = hl;
        } else {
            size_t ab = (size_t)grow * 2048;
            float h0v = bf2f(h0src[ab + ghc]) + bf2f(h0src[ab + 1024 + ghc]);
            float hs = h0v + hn;
            u16 sh = f2bf(hs);
            float sl = hs - bf2f(sh);
            hsumdst[ab + ghc] = sh;
            hsumdst[ab + 1024 + ghc] = f2bf(sl);
            seqdst[(size_t)grow * 512 + ghc] = sh;
        }
    }
}

// ------------------------------------------------------------------- MLP -----
// y = act(A[R x 512] @ Bw[n x k]^T-style + bias). BM=64 (blockIdx.y of 1024), BN=128 (blockIdx.x of 4).
template <int RELU, int FINAL>
__global__ __launch_bounds__(256) void mlp_gemm(
    const u16* __restrict__ A, const u16* __restrict__ Bw, const float* __restrict__ bias,
    u16* __restrict__ ybf, float* __restrict__ yf32)
{
    __shared__ char smem[36864];
    u16* sA = (u16*)smem;             // [64][72]
    u16* sB = (u16*)(smem + 9216);    // [128][72]

    const int tid = threadIdx.x;
    const int lane = tid & 63, wid = tid >> 6;
    const int row0 = blockIdx.y * 64;
    const int n0 = blockIdx.x * 128;
    const int wn = wid * 32;
    const int fm = lane & 15;
    const int fkbase = (lane >> 4) * 8;

    f32x4 acc[4][2];
#pragma unroll
    for (int m = 0; m < 4; ++m) { acc[m][0] = (f32x4)0.f; acc[m][1] = (f32x4)0.f; }

    for (int kk = 0; kk < 8; ++kk) {
        const int k0 = kk * 64;
        __syncthreads();
#pragma unroll
        for (int r = 0; r < 2; ++r) {
            int c = tid + r * 256;
            int row = c >> 3, cc = (c & 7) * 8;
            *(bf16x8*)&sA[row * 72 + cc] = *(const bf16x8*)&A[(size_t)(row0 + row) * 512 + k0 + cc];
        }
#pragma unroll
        for (int r = 0; r < 4; ++r) {
            int c = tid + r * 256;
            int row = c >> 3, cc = (c & 7) * 8;
            *(bf16x8*)&sB[row * 72 + cc] = *(const bf16x8*)&Bw[(size_t)(n0 + row) * 512 + k0 + cc];
        }
        __syncthreads();
#pragma unroll
        for (int kf = 0; kf < 2; ++kf) {
            const int kb = kf * 32 + fkbase;
            bf16x8 b0 = *(const bf16x8*)&sB[(wn + fm) * 72 + kb];
            bf16x8 b1 = *(const bf16x8*)&sB[(wn + 16 + fm) * 72 + kb];
#pragma unroll
            for (int m = 0; m < 4; ++m) {
                bf16x8 ah = *(const bf16x8*)&sA[(m * 16 + fm) * 72 + kb];
                acc[m][0] = __builtin_amdgcn_mfma_f32_16x16x32_bf16(ah, b0, acc[m][0], 0, 0, 0);
                acc[m][1] = __builtin_amdgcn_mfma_f32_16x16x32_bf16(ah, b1, acc[m][1], 0, 0, 0);
            }
        }
    }

    __syncthreads();
    float* sG = (float*)smem;  // [64][132]
#pragma unroll
    for (int m = 0; m < 4; ++m)
#pragma unroll
        for (int n = 0; n < 2; ++n)
#pragma unroll
            for (int r = 0; r < 4; ++r) {
                int row = m * 16 + (lane >> 4) * 4 + r;
                int col = wn + n * 16 + fm;
                sG[row * 132 + col] = acc[m][n][r];
            }
    __syncthreads();

    const int row = tid >> 2;
    const int cg = (tid & 3) * 32;
    const size_t r = (size_t)row0 + row;
#pragma unroll
    for (int c = cg; c < cg + 32; c += 4) {
        float4 g = *(const float4*)&sG[row * 132 + c];
        float4 b = *(const float4*)&bias[n0 + c];
        float v0 = g.x + b.x, v1 = g.y + b.y, v2 = g.z + b.z, v3 = g.w + b.w;
        if (RELU) {
            v0 = fmaxf(v0, 0.f); v1 = fmaxf(v1, 0.f); v2 = fmaxf(v2, 0.f); v3 = fmaxf(v3, 0.f);
        }
        if (!FINAL) {
            ushort4 p;
            p.x = f2bf(v0); p.y = f2bf(v1); p.z = f2bf(v2); p.w = f2bf(v3);
            *(ushort4*)&ybf[r * 512 + n0 + c] = p;
        } else {
            int tt = (int)(r >> 9), bb = (int)(r & 511);  // seq row r = t*512 + b
            float4 o; o.x = v0; o.y = v1; o.z = v2; o.w = v3;
            *(float4*)&yf32[((size_t)bb * 128 + tt) * 512 + n0 + c] = o;
        }
    }
}

// ---------------------------------------------------------------- launch -----
extern "C" void kernel_launch(void* const* d_in, const int* in_sizes, int n_in,
                              void* d_out, int out_size, void* d_ws, size_t ws_size,
                              hipStream_t stream) {
    const float* x    = (const float*)d_in[0];
    const float* W_ih = (const float*)d_in[1];
    const float* W_hh = (const float*)d_in[2];
    const float* b_ih = (const float*)d_in[3];
    const float* b_hh = (const float*)d_in[4];
    const float* fc1w = (const float*)d_in[5];
    const float* fc1b = (const float*)d_in[6];
    const float* fc2w = (const float*)d_in[7];
    const float* fc2b = (const float*)d_in[8];
    const float* fc3w = (const float*)d_in[9];
    const float* fc3b = (const float*)d_in[10];

    char* ws = (char*)d_ws;
    u16* Bpack = (u16*)(ws);                          // 2*2048*1024*2 = 8,388,608 B
    u16* fcw   = (u16*)(ws + 8388608);                // 3*512*512*2  = 1,572,864 B
    float* bsum = (float*)(ws + 9961472);             // 2*2048*4     = 16,384 B
    u16* A0[2] = { (u16*)(ws + 9977856), (u16*)(ws + 9977856 + 2097152) };
    u16* A1[2] = { (u16*)(ws + 14172160), (u16*)(ws + 14172160 + 2097152) };
    float* c0 = (float*)(ws + 18366464);              // 512*512*4
    float* c1 = (float*)(ws + 19415040);              // 512*512*4
    u16* seqb = (u16*)(ws + 20463616);                // 128*512*512*2 = 67,108,864 (also reused as y2)
    u16* y1   = (u16*)(ws + 87572480);                // 67,108,864
    float* out = (float*)d_out;

    prepack<<<dim3(512), dim3(256), 0, stream>>>(W_ih, W_hh, b_ih, b_hh, fc1w, fc2w, fc3w,
                                                 Bpack, bsum, fcw);
    initbufs<<<dim3(512), dim3(256), 0, stream>>>(x, A0[0], A1[0], c0, c1);

    for (int t = 0; t < 128; ++t) {
        int cur = t & 1, nxt = cur ^ 1;
        // layer 0: reads A0[cur]=[x_l, h0]; writes h0 -> A1[cur] cols[0:512) and A0[nxt] cols[512:1024)
        lstm_step<0><<<dim3(16, 8), dim3(256), 0, stream>>>(
            A0[cur], Bpack, bsum, c0,
            A1[cur], 0, A0[nxt], 512, nullptr, nullptr, nullptr);
        // layer 1: reads A1[cur]=[h0(t), h1(t-1)]; writes h1 -> A1[nxt] cols[512:1024);
        //          h_sum -> A0[nxt] cols[0:512) + seqbuf[t]
        lstm_step<1><<<dim3(16, 8), dim3(256), 0, stream>>>(
            A1[cur], Bpack + 2048 * 1024, bsum + 2048, c1,
            A1[nxt], 512, nullptr, 0, A1[cur], A0[nxt], seqb + (size_t)t * 512 * 512);
    }

    mlp_gemm<1, 0><<<dim3(4, 1024), dim3(256), 0, stream>>>(seqb, fcw, fc1b, y1, nullptr);
    mlp_gemm<1, 0><<<dim3(4, 1024), dim3(256), 0, stream>>>(y1, fcw + 512 * 512, fc2b, seqb, nullptr);
    mlp_gemm<0, 1><<<dim3(4, 1024), dim3(256), 0, stream>>>(seqb, fcw + 2 * 512 * 512, fc3b, nullptr, out);
}

// Round 2
// 3503.303 us; speedup vs baseline: 1.7927x; 1.7927x over previous
//
#include <hip/hip_runtime.h>
#include <cstdint>
#include <cstddef>

// DecoderLSTM: 2-layer LSTM (B=512,H=512,T=128) + 3-layer MLP head.
// bf16 MFMA; A-operand bf16 hi+lo (K doubled) for accuracy; fp32 cell state.
// Round 2: lstm_step rebuilt — 256 blocks (1/CU), global_load_lds staging with
// XOR-involution swizzle (pre-swizzled global source + swizzled ds_read),
// 1 barrier per K-chunk, XCD-bijective block mapping.

using u16 = unsigned short;
typedef __attribute__((ext_vector_type(8))) short bf16x8;
typedef __attribute__((ext_vector_type(4))) float f32x4;

__device__ __forceinline__ u16 f2bf(float f) {
    union { float f; uint32_t u; } v; v.f = f;
    uint32_t u = v.u;
    uint32_t r = (u + 0x7fffu + ((u >> 16) & 1u)) >> 16;
    return (u16)r;
}
__device__ __forceinline__ float bf2f(u16 h) {
    union { uint32_t u; float f; } v; v.u = ((uint32_t)h) << 16;
    return v.f;
}
__device__ __forceinline__ float tanh_fast(float v) {
    float a = fabsf(v);
    float t = __expf(-2.f * a);
    float r = (1.f - t) / (1.f + t);
    return copysignf(r, v);
}
__device__ __forceinline__ float sigmoid_fast(float v) {
    return 1.f / (1.f + __expf(-v));
}

__device__ __forceinline__ void gl_lds16(const u16* g, char* l) {
    __builtin_amdgcn_global_load_lds((const __attribute__((address_space(1))) char*)(const char*)g,
                                     (__attribute__((address_space(3))) char*)l, 16, 0, 0);
}

// Swizzled LDS read: tile is [64 rows][64 bf16] linear (128B rows = 8 x 16B units),
// unit u' holds global col-unit u'^(row&7). Read global (row, cu) -> unit row*8 + (cu^(row&7)).
__device__ __forceinline__ bf16x8 lds_read_sw(const u16* tile, int row, int cu) {
    int unit = (row << 3) | (cu ^ (row & 7));
    return *(const bf16x8*)&tile[unit << 3];
}

// ---------------------------------------------------------------- prepack ----
// Bpack[l][np][k], np = hcol*4 + gate (i,f,g,o), k: 0..511 = W_ih, 512..1023 = W_hh
__global__ __launch_bounds__(256) void prepack(
    const float* __restrict__ W_ih, const float* __restrict__ W_hh,
    const float* __restrict__ b_ih, const float* __restrict__ b_hh,
    const float* __restrict__ fc1w, const float* __restrict__ fc2w, const float* __restrict__ fc3w,
    u16* __restrict__ Bpack, float* __restrict__ bsumv, u16* __restrict__ fcw)
{
    int stride = gridDim.x * blockDim.x;
    int tid0 = blockIdx.x * blockDim.x + threadIdx.x;
    for (int idx = tid0; idx < 2 * 2048 * 1024; idx += stride) {
        int l = idx >> 21;
        int rem = idx & ((1 << 21) - 1);
        int np = rem >> 10;
        int k = rem & 1023;
        int n = (np & 3) * 512 + (np >> 2);
        float v = (k < 512) ? W_ih[((size_t)l * 2048 + n) * 512 + k]
                            : W_hh[((size_t)l * 2048 + n) * 512 + (k - 512)];
        Bpack[idx] = f2bf(v);
    }
    for (int idx = tid0; idx < 2 * 2048; idx += stride) {
        int l = idx >> 11;
        int np = idx & 2047;
        int n = (np & 3) * 512 + (np >> 2);
        bsumv[idx] = b_ih[l * 2048 + n] + b_hh[l * 2048 + n];
    }
    for (int idx = tid0; idx < 3 * 512 * 512; idx += stride) {
        const float* w = idx < 262144 ? fc1w : (idx < 524288 ? fc2w : fc3w);
        fcw[idx] = f2bf(w[idx & 262143]);
    }
}

// A buffers: [512][2048] bf16: [0:512)=x/hsum hi, [512:1024)=h hi, [1024:1536)=x lo, [1536:2048)=h lo
__global__ __launch_bounds__(256) void initbufs(
    const float* __restrict__ x, u16* __restrict__ A0_0, u16* __restrict__ A1_0,
    float* __restrict__ c0, float* __restrict__ c1)
{
    int stride = gridDim.x * blockDim.x;
    int tid0 = blockIdx.x * blockDim.x + threadIdx.x;
    for (int idx = tid0; idx < 512 * 512; idx += stride) {
        int row = idx >> 9, col = idx & 511;
        float xv = x[idx];
        u16 hi = f2bf(xv);
        float lo = xv - bf2f(hi);
        size_t b = (size_t)row * 2048;
        A0_0[b + col] = hi;
        A0_0[b + 1024 + col] = f2bf(lo);
        A0_0[b + 512 + col] = 0;
        A0_0[b + 1536 + col] = 0;
        A1_0[b + 512 + col] = 0;
        A1_0[b + 1536 + col] = 0;
        c0[idx] = 0.f;
        c1[idx] = 0.f;
    }
}

// --------------------------------------------------------------- lstm step ---
// 256 blocks x 256 thr. Block: 64 rows x 64 n'-cols, K=1024 (x512+h512), A hi+lo.
// 4 waves, each a 32x32 quadrant (2m x 2n frags of 16x16), 16 MFMA + 12 ds_read_b128/chunk.
template <int IS_L1>
__global__ __launch_bounds__(256) void lstm_step(
    const u16* __restrict__ A, const u16* __restrict__ Bp, const float* __restrict__ bsumv,
    float* cbuf, u16* hdst1, int hoff1, u16* hdst2, int hoff2,
    const u16* h0src, u16* hsumdst, u16* seqdst)
{
    __shared__ char smem[49152];   // 2 bufs x 3 tiles x 8KB

    // XCD-bijective mapping: xcd = id&7 owns n-blocks [4*xcd, 4*xcd+4) for all 8 row-groups.
    const int id = blockIdx.x;
    const int xcd = id & 7, slot = id >> 3;
    const int nb = xcd * 4 + (slot & 3);   // 0..31
    const int rg = slot >> 2;              // 0..7
    const int n0 = nb * 64;
    const int row0 = rg * 64;

    const int tid = threadIdx.x;
    const int lane = tid & 63, wid = tid >> 6;
    const int wm = (wid >> 1) * 32;        // wave row offset in tile
    const int wn = (wid & 1) * 32;         // wave col offset in tile
    const int fm = lane & 15;
    const int q = lane >> 4;               // 0..3

    // Staging precompute: wave w stages LDS 16B-units [w*128, w*128+128) of each tile
    // (2 instrs x 64 lanes). LDS linear; global source pre-swizzled by the involution.
    const int s0 = wid * 128 + lane;
    const int s1 = s0 + 64;
    const int r0s = s0 >> 3, c0s = ((s0 & 7) ^ (r0s & 7)) << 3;
    const int r1s = s1 >> 3, c1s = ((s1 & 7) ^ (r1s & 7)) << 3;
    const size_t aO0 = (size_t)(row0 + r0s) * 2048 + c0s;
    const size_t aO1 = (size_t)(row0 + r1s) * 2048 + c1s;
    const size_t bO0 = (size_t)(n0 + r0s) * 1024 + c0s;
    const size_t bO1 = (size_t)(n0 + r1s) * 1024 + c1s;
    const int d0 = wid * 2048;             // byte offset within tile (instr 0)
    const int d1 = d0 + 1024;              // instr 1

    f32x4 acc[2][2];
    acc[0][0] = (f32x4)0.f; acc[0][1] = (f32x4)0.f;
    acc[1][0] = (f32x4)0.f; acc[1][1] = (f32x4)0.f;

#define TILEB(buf, t) (smem + (buf) * 24576 + (t) * 8192)

    auto stage = [&](int buf, int k0) {
        char* th = TILEB(buf, 0);
        char* tl = TILEB(buf, 1);
        char* tb = TILEB(buf, 2);
        gl_lds16(A + aO0 + k0, th + d0);
        gl_lds16(A + aO1 + k0, th + d1);
        gl_lds16(A + aO0 + 1024 + k0, tl + d0);
        gl_lds16(A + aO1 + 1024 + k0, tl + d1);
        gl_lds16(Bp + bO0 + k0, tb + d0);
        gl_lds16(Bp + bO1 + k0, tb + d1);
    };

    stage(0, 0);
    __syncthreads();

    for (int c = 0; c < 16; ++c) {
        const int cur = c & 1;
        if (c < 15) stage(cur ^ 1, (c + 1) * 64);

        const u16* sAhi = (const u16*)TILEB(cur, 0);
        const u16* sAlo = (const u16*)TILEB(cur, 1);
        const u16* sB   = (const u16*)TILEB(cur, 2);

#pragma unroll
        for (int kf = 0; kf < 2; ++kf) {
            const int cu = kf * 4 + q;
            bf16x8 b0 = lds_read_sw(sB, wn + fm, cu);
            bf16x8 b1 = lds_read_sw(sB, wn + 16 + fm, cu);
            bf16x8 ah0 = lds_read_sw(sAhi, wm + fm, cu);
            bf16x8 ah1 = lds_read_sw(sAhi, wm + 16 + fm, cu);
            bf16x8 al0 = lds_read_sw(sAlo, wm + fm, cu);
            bf16x8 al1 = lds_read_sw(sAlo, wm + 16 + fm, cu);
            acc[0][0] = __builtin_amdgcn_mfma_f32_16x16x32_bf16(ah0, b0, acc[0][0], 0, 0, 0);
            acc[0][1] = __builtin_amdgcn_mfma_f32_16x16x32_bf16(ah0, b1, acc[0][1], 0, 0, 0);
            acc[1][0] = __builtin_amdgcn_mfma_f32_16x16x32_bf16(ah1, b0, acc[1][0], 0, 0, 0);
            acc[1][1] = __builtin_amdgcn_mfma_f32_16x16x32_bf16(ah1, b1, acc[1][1], 0, 0, 0);
            acc[0][0] = __builtin_amdgcn_mfma_f32_16x16x32_bf16(al0, b0, acc[0][0], 0, 0, 0);
            acc[0][1] = __builtin_amdgcn_mfma_f32_16x16x32_bf16(al0, b1, acc[0][1], 0, 0, 0);
            acc[1][0] = __builtin_amdgcn_mfma_f32_16x16x32_bf16(al1, b0, acc[1][0], 0, 0, 0);
            acc[1][1] = __builtin_amdgcn_mfma_f32_16x16x32_bf16(al1, b1, acc[1][1], 0, 0, 0);
        }
        __syncthreads();   // drains vmcnt (stage) + lgkm, then barrier
    }
#undef TILEB

    // Epilogue: acc -> sG (fp32, [64][68]) -> fused LSTM elementwise.
    float* sG = (float*)smem;
#pragma unroll
    for (int m = 0; m < 2; ++m)
#pragma unroll
        for (int n = 0; n < 2; ++n)
#pragma unroll
            for (int r = 0; r < 4; ++r) {
                int row = wm + m * 16 + q * 4 + r;
                int col = wn + n * 16 + fm;
                sG[row * 68 + col] = acc[m][n][r];
            }
    __syncthreads();

#pragma unroll
    for (int j = 0; j < 4; ++j) {
        int cell = tid + j * 256;           // 64 rows x 16 hcols
        int row = cell >> 4, hc = cell & 15;
        const float4 g4 = *(const float4*)&sG[row * 68 + hc * 4];
        const float4 b4 = *(const float4*)&bsumv[n0 + hc * 4];
        float gi = g4.x + b4.x, gf = g4.y + b4.y, gg = g4.z + b4.z, go = g4.w + b4.w;
        int grow = row0 + row;
        int ghc = (n0 >> 2) + hc;
        int cidx = grow * 512 + ghc;
        float c_old = cbuf[cidx];
        float is = sigmoid_fast(gi);
        float fs = sigmoid_fast(gf);
        float os = sigmoid_fast(go);
        float gt = tanh_fast(gg);
        float cn = fs * c_old + is * gt;
        float hn = os * tanh_fast(cn);
        cbuf[cidx] = cn;
        u16 hh = f2bf(hn);
        float hlo = hn - bf2f(hh);
        u16 hl = f2bf(hlo);
        size_t base1 = (size_t)grow * 2048 + hoff1;
        hdst1[base1 + ghc] = hh;
        hdst1[base1 + 1024 + ghc] = hl;
        if (!IS_L1) {
            size_t base2 = (size_t)grow * 2048 + hoff2;
            hdst2[base2 + ghc] = hh;
            hdst2[base2 + 1024 + ghc] = hl;
        } else {
            size_t ab = (size_t)grow * 2048;
            float h0v = bf2f(h0src[ab + ghc]) + bf2f(h0src[ab + 1024 + ghc]);
            float hs = h0v + hn;
            u16 sh = f2bf(hs);
            float sl = hs - bf2f(sh);
            hsumdst[ab + ghc] = sh;
            hsumdst[ab + 1024 + ghc] = f2bf(sl);
            seqdst[(size_t)grow * 512 + ghc] = sh;
        }
    }
}

// ------------------------------------------------------------------- MLP -----
// Unchanged from round 1 (known-correct; ~6% of runtime).
template <int RELU, int FINAL>
__global__ __launch_bounds__(256) void mlp_gemm(
    const u16* __restrict__ A, const u16* __restrict__ Bw, const float* __restrict__ bias,
    u16* __restrict__ ybf, float* __restrict__ yf32)
{
    __shared__ char smem[36864];
    u16* sA = (u16*)smem;             // [64][72]
    u16* sB = (u16*)(smem + 9216);    // [128][72]

    const int tid = threadIdx.x;
    const int lane = tid & 63, wid = tid >> 6;
    const int row0 = blockIdx.y * 64;
    const int n0 = blockIdx.x * 128;
    const int wn = wid * 32;
    const int fm = lane & 15;
    const int fkbase = (lane >> 4) * 8;

    f32x4 acc[4][2];
#pragma unroll
    for (int m = 0; m < 4; ++m) { acc[m][0] = (f32x4)0.f; acc[m][1] = (f32x4)0.f; }

    for (int kk = 0; kk < 8; ++kk) {
        const int k0 = kk * 64;
        __syncthreads();
#pragma unroll
        for (int r = 0; r < 2; ++r) {
            int c = tid + r * 256;
            int row = c >> 3, cc = (c & 7) * 8;
            *(bf16x8*)&sA[row * 72 + cc] = *(const bf16x8*)&A[(size_t)(row0 + row) * 512 + k0 + cc];
        }
#pragma unroll
        for (int r = 0; r < 4; ++r) {
            int c = tid + r * 256;
            int row = c >> 3, cc = (c & 7) * 8;
            *(bf16x8*)&sB[row * 72 + cc] = *(const bf16x8*)&Bw[(size_t)(n0 + row) * 512 + k0 + cc];
        }
        __syncthreads();
#pragma unroll
        for (int kf = 0; kf < 2; ++kf) {
            const int kb = kf * 32 + fkbase;
            bf16x8 b0 = *(const bf16x8*)&sB[(wn + fm) * 72 + kb];
            bf16x8 b1 = *(const bf16x8*)&sB[(wn + 16 + fm) * 72 + kb];
#pragma unroll
            for (int m = 0; m < 4; ++m) {
                bf16x8 ah = *(const bf16x8*)&sA[(m * 16 + fm) * 72 + kb];
                acc[m][0] = __builtin_amdgcn_mfma_f32_16x16x32_bf16(ah, b0, acc[m][0], 0, 0, 0);
                acc[m][1] = __builtin_amdgcn_mfma_f32_16x16x32_bf16(ah, b1, acc[m][1], 0, 0, 0);
            }
        }
    }

    __syncthreads();
    float* sG = (float*)smem;  // [64][132]
#pragma unroll
    for (int m = 0; m < 4; ++m)
#pragma unroll
        for (int n = 0; n < 2; ++n)
#pragma unroll
            for (int r = 0; r < 4; ++r) {
                int row = m * 16 + (lane >> 4) * 4 + r;
                int col = wn + n * 16 + fm;
                sG[row * 132 + col] = acc[m][n][r];
            }
    __syncthreads();

    const int row = tid >> 2;
    const int cg = (tid & 3) * 32;
    const size_t r = (size_t)row0 + row;
#pragma unroll
    for (int c = cg; c < cg + 32; c += 4) {
        float4 g = *(const float4*)&sG[row * 132 + c];
        float4 b = *(const float4*)&bias[n0 + c];
        float v0 = g.x + b.x, v1 = g.y + b.y, v2 = g.z + b.z, v3 = g.w + b.w;
        if (RELU) {
            v0 = fmaxf(v0, 0.f); v1 = fmaxf(v1, 0.f); v2 = fmaxf(v2, 0.f); v3 = fmaxf(v3, 0.f);
        }
        if (!FINAL) {
            ushort4 p;
            p.x = f2bf(v0); p.y = f2bf(v1); p.z = f2bf(v2); p.w = f2bf(v3);
            *(ushort4*)&ybf[r * 512 + n0 + c] = p;
        } else {
            int tt = (int)(r >> 9), bb = (int)(r & 511);  // seq row r = t*512 + b
            float4 o; o.x = v0; o.y = v1; o.z = v2; o.w = v3;
            *(float4*)&yf32[((size_t)bb * 128 + tt) * 512 + n0 + c] = o;
        }
    }
}

// ---------------------------------------------------------------- launch -----
extern "C" void kernel_launch(void* const* d_in, const int* in_sizes, int n_in,
                              void* d_out, int out_size, void* d_ws, size_t ws_size,
                              hipStream_t stream) {
    const float* x    = (const float*)d_in[0];
    const float* W_ih = (const float*)d_in[1];
    const float* W_hh = (const float*)d_in[2];
    const float* b_ih = (const float*)d_in[3];
    const float* b_hh = (const float*)d_in[4];
    const float* fc1w = (const float*)d_in[5];
    const float* fc1b = (const float*)d_in[6];
    const float* fc2w = (const float*)d_in[7];
    const float* fc2b = (const float*)d_in[8];
    const float* fc3w = (const float*)d_in[9];
    const float* fc3b = (const float*)d_in[10];

    char* ws = (char*)d_ws;
    u16* Bpack = (u16*)(ws);                          // 8,388,608 B
    u16* fcw   = (u16*)(ws + 8388608);                // 1,572,864 B
    float* bsum = (float*)(ws + 9961472);             // 16,384 B
    u16* A0[2] = { (u16*)(ws + 9977856), (u16*)(ws + 9977856 + 2097152) };
    u16* A1[2] = { (u16*)(ws + 14172160), (u16*)(ws + 14172160 + 2097152) };
    float* c0 = (float*)(ws + 18366464);
    float* c1 = (float*)(ws + 19415040);
    u16* seqb = (u16*)(ws + 20463616);                // 67,108,864 (reused as y2)
    u16* y1   = (u16*)(ws + 87572480);                // 67,108,864
    float* out = (float*)d_out;

    prepack<<<dim3(512), dim3(256), 0, stream>>>(W_ih, W_hh, b_ih, b_hh, fc1w, fc2w, fc3w,
                                                 Bpack, bsum, fcw);
    initbufs<<<dim3(512), dim3(256), 0, stream>>>(x, A0[0], A1[0], c0, c1);

    for (int t = 0; t < 128; ++t) {
        int cur = t & 1, nxt = cur ^ 1;
        lstm_step<0><<<dim3(256), dim3(256), 0, stream>>>(
            A0[cur], Bpack, bsum, c0,
            A1[cur], 0, A0[nxt], 512, nullptr, nullptr, nullptr);
        lstm_step<1><<<dim3(256), dim3(256), 0, stream>>>(
            A1[cur], Bpack + 2048 * 1024, bsum + 2048, c1,
            A1[nxt], 512, nullptr, 0, A1[cur], A0[nxt], seqb + (size_t)t * 512 * 512);
    }

    mlp_gemm<1, 0><<<dim3(4, 1024), dim3(256), 0, stream>>>(seqb, fcw, fc1b, y1, nullptr);
    mlp_gemm<1, 0><<<dim3(4, 1024), dim3(256), 0, stream>>>(y1, fcw + 512 * 512, fc2b, seqb, nullptr);
    mlp_gemm<0, 1><<<dim3(4, 1024), dim3(256), 0, stream>>>(seqb, fcw + 2 * 512 * 512, fc3b, nullptr, out);
}